// Round 1
// baseline (109.526 us; speedup 1.0000x reference)
//
#include <hip/hip_runtime.h>
#include <stdint.h>

// Problem dims (fixed by reference)
#define BB   8
#define SS   2048
#define DIN  1024
#define DOUT 64

typedef __bf16 bf16_t;
typedef __bf16 bf16x8 __attribute__((ext_vector_type(8)));
typedef float  f32x4  __attribute__((ext_vector_type(4)));
typedef unsigned int u32x4 __attribute__((ext_vector_type(4)));

#define LOG2E 1.44269504088896f

// ---------------------------------------------------------------------------
// Kernel 0: pre-pack weights (1024x64 fp32) into bf16 MFMA B-fragment order.
// Layout: fw[proj][kk=0..31][nt=0..3][lane=0..63][j=0..7]
//   value = W[k][col],  k = kk*32 + (lane>>4)*8 + j,  col = nt*16 + (lane&15)
// Q weights (proj==2) are scaled by 1/sqrt(64) = 0.125 (exact in bf16).
// ---------------------------------------------------------------------------
__global__ void prep_weights(const float* __restrict__ Kw,
                             const float* __restrict__ Vw,
                             const float* __restrict__ Qw,
                             bf16_t* __restrict__ fw) {
    int proj = blockIdx.x >> 4;   // 0..2
    int seg  = blockIdx.x & 15;   // 0..15
    const float* W = (proj == 0) ? Kw : (proj == 1) ? Vw : Qw;
    float scale = (proj == 2) ? 0.125f : 1.0f;
    bf16_t* out = fw + proj * 65536;
    int base = seg * 4096;
#pragma unroll
    for (int i = 0; i < 16; ++i) {
        int idx  = base + i * 256 + threadIdx.x;
        int j    = idx & 7;
        int lane = (idx >> 3) & 63;
        int nt   = (idx >> 9) & 3;
        int kk   = idx >> 11;
        int k    = kk * 32 + (lane >> 4) * 8 + j;
        int col  = nt * 16 + (lane & 15);
        out[idx] = (bf16_t)(W[k * DOUT + col] * scale);
    }
}

// ---------------------------------------------------------------------------
// Kernel 1: projection GEMM  [16384,1024](fp32) x [1024,64](bf16) -> bf16
// Block: 256 threads = 4 waves; each wave computes a 16x64 output strip.
// B-fragments staged to LDS in 32KB chunks (linear copy of fragment buffer).
// ---------------------------------------------------------------------------
__global__ __launch_bounds__(256) void proj_kernel(
    const float* __restrict__ Xk, const float* __restrict__ Xv,
    const float* __restrict__ Xq, const bf16_t* __restrict__ fw,
    bf16_t* __restrict__ outK, bf16_t* __restrict__ outV,
    bf16_t* __restrict__ outQ) {
    __shared__ __align__(16) bf16_t lds[16384];  // 32 KB chunk of fw

    int proj = blockIdx.y;
    const float* X  = (proj == 0) ? Xk : (proj == 1) ? Xv : Xq;
    bf16_t* out     = (proj == 0) ? outK : (proj == 1) ? outV : outQ;
    const bf16_t* fwp = fw + proj * 65536;

    int tid  = threadIdx.x;
    int lane = tid & 63;
    int w    = tid >> 6;
    int row0 = blockIdx.x * 64 + w * 16;
    int arow = row0 + (lane & 15);
    const float* aptr = X + (size_t)arow * DIN + ((lane >> 4) * 8);

    f32x4 acc[4];
#pragma unroll
    for (int nt = 0; nt < 4; ++nt) acc[nt] = (f32x4)(0.0f);

    for (int c = 0; c < 4; ++c) {
        __syncthreads();
        // stage 32KB chunk c (linear copy, coalesced, conflict-free)
        const u32x4* src = (const u32x4*)(fwp + c * 16384);
        u32x4* dst = (u32x4*)lds;
#pragma unroll
        for (int i = 0; i < 8; ++i) dst[tid + 256 * i] = src[tid + 256 * i];
        __syncthreads();

#pragma unroll
        for (int kkl = 0; kkl < 8; ++kkl) {
            int kglob = c * 256 + kkl * 32;
            f32x4 a0 = *(const f32x4*)(aptr + kglob);
            f32x4 a1 = *(const f32x4*)(aptr + kglob + 4);
            bf16x8 af;
            af[0] = (bf16_t)a0[0]; af[1] = (bf16_t)a0[1];
            af[2] = (bf16_t)a0[2]; af[3] = (bf16_t)a0[3];
            af[4] = (bf16_t)a1[0]; af[5] = (bf16_t)a1[1];
            af[6] = (bf16_t)a1[2]; af[7] = (bf16_t)a1[3];
#pragma unroll
            for (int nt = 0; nt < 4; ++nt) {
                bf16x8 bfv = *(const bf16x8*)((const char*)lds +
                                ((size_t)((kkl * 4 + nt) * 64 + lane) * 16));
                acc[nt] = __builtin_amdgcn_mfma_f32_16x16x32_bf16(af, bfv, acc[nt], 0, 0, 0);
            }
        }
    }

    // write bf16 [row][64]; C/D layout: col = lane&15 (+16*nt), row = (lane>>4)*4 + r
#pragma unroll
    for (int nt = 0; nt < 4; ++nt) {
#pragma unroll
        for (int r = 0; r < 4; ++r) {
            int row = row0 + (lane >> 4) * 4 + r;
            int col = nt * 16 + (lane & 15);
            out[(size_t)row * DOUT + col] = (bf16_t)acc[nt][r];
        }
    }
}

// ---------------------------------------------------------------------------
// Kernel 2: causal flash attention, bf16 MFMA, fp32 accum.
// Grid: (32 q-tiles, 8 batches). Block: 256 thr = 4 waves x 16 q-rows.
// K LDS:  [key][d] with byte ^= (key&7)<<4 swizzle (kills 32-way conflict)
// V LDS:  transposed [d][key], byte ^= (d&7)<<4
// P LDS:  per-wave [q][key], byte ^= (q&7)<<4
// ---------------------------------------------------------------------------
__global__ __launch_bounds__(256) void attn_kernel(
    const bf16_t* __restrict__ Kp, const bf16_t* __restrict__ Vp,
    const bf16_t* __restrict__ Qp, float* __restrict__ out) {
    __shared__ __align__(16) bf16_t Klds[64 * 64];      // 8 KB
    __shared__ __align__(16) bf16_t Vlds[64 * 64];      // 8 KB (transposed)
    __shared__ __align__(16) bf16_t Plds[4][16 * 64];   // 8 KB

    int tid   = threadIdx.x;
    int lane  = tid & 63;
    int w     = tid >> 6;
    int qtile = blockIdx.x;
    int batch = blockIdx.y;

    const bf16_t* Kb = Kp + (size_t)batch * SS * DOUT;
    const bf16_t* Vb = Vp + (size_t)batch * SS * DOUT;
    const bf16_t* Qb = Qp + (size_t)batch * SS * DOUT;

    // Q fragments (Q already scaled by 1/8): A-frag row = lane&15
    bf16x8 aq[2];
    {
        int r = qtile * 64 + w * 16 + (lane & 15);
        const bf16_t* qp = Qb + (size_t)r * DOUT + (lane >> 4) * 8;
        aq[0] = *(const bf16x8*)(qp);
        aq[1] = *(const bf16x8*)(qp + 32);
    }

    float m[4], lsum[4];
    f32x4 acc[4];
#pragma unroll
    for (int r = 0; r < 4; ++r) { m[r] = -1e30f; lsum[r] = 0.0f; }
#pragma unroll
    for (int nt = 0; nt < 4; ++nt) acc[nt] = (f32x4)(0.0f);

    int ntiles = qtile + 1;
    for (int j = 0; j < ntiles; ++j) {
        __syncthreads();
        // ---- stage K tile (swizzled) and V tile (transposed, swizzled) ----
#pragma unroll
        for (int i = 0; i < 2; ++i) {
            int c   = tid + 256 * i;          // 0..511
            int key = c >> 3;
            int d0  = (c & 7) * 8;
            u32x4 v = *(const u32x4*)(Kb + ((size_t)(j * 64 + key)) * DOUT + d0);
            *(u32x4*)((char*)Klds + key * 128 + ((d0 * 2) ^ ((key & 7) << 4))) = v;
        }
#pragma unroll
        for (int i = 0; i < 2; ++i) {
            int c   = tid + 256 * i;
            int key = c >> 3;
            int d0  = (c & 7) * 8;
            bf16x8 v = *(const bf16x8*)(Vb + ((size_t)(j * 64 + key)) * DOUT + d0);
#pragma unroll
            for (int jj = 0; jj < 8; ++jj) {
                int d = d0 + jj;
                *(bf16_t*)((char*)Vlds + d * 128 + ((key * 2) ^ ((d & 7) << 4))) = v[jj];
            }
        }
        __syncthreads();

        // ---- S = Q K^T (scaled) ----
        f32x4 sfr[4];
#pragma unroll
        for (int nt = 0; nt < 4; ++nt) sfr[nt] = (f32x4)(0.0f);
#pragma unroll
        for (int kk = 0; kk < 2; ++kk) {
            int d0 = kk * 32 + (lane >> 4) * 8;
#pragma unroll
            for (int nt = 0; nt < 4; ++nt) {
                int key = nt * 16 + (lane & 15);
                bf16x8 bk = *(const bf16x8*)((char*)Klds + key * 128 +
                                             ((d0 * 2) ^ ((key & 7) << 4)));
                sfr[nt] = __builtin_amdgcn_mfma_f32_16x16x32_bf16(aq[kk], bk, sfr[nt], 0, 0, 0);
            }
        }

        // ---- causal mask (only diagonal tile) ----
        if (j == qtile) {
#pragma unroll
            for (int nt = 0; nt < 4; ++nt) {
                int key = nt * 16 + (lane & 15);
#pragma unroll
                for (int r = 0; r < 4; ++r) {
                    int q = w * 16 + (lane >> 4) * 4 + r;
                    if (key > q) sfr[nt][r] = -1e30f;
                }
            }
        }

        // ---- online softmax (rows live in 16-lane groups) ----
        float pf[4][4];  // [nt][r]
#pragma unroll
        for (int r = 0; r < 4; ++r) {
            float mx = fmaxf(fmaxf(sfr[0][r], sfr[1][r]), fmaxf(sfr[2][r], sfr[3][r]));
            mx = fmaxf(mx, __shfl_xor(mx, 1));
            mx = fmaxf(mx, __shfl_xor(mx, 2));
            mx = fmaxf(mx, __shfl_xor(mx, 4));
            mx = fmaxf(mx, __shfl_xor(mx, 8));
            float mn = fmaxf(m[r], mx);
            float scale = exp2f((m[r] - mn) * LOG2E);
            m[r] = mn;
            float rs = 0.0f;
#pragma unroll
            for (int nt = 0; nt < 4; ++nt) {
                float p = exp2f((sfr[nt][r] - mn) * LOG2E);
                pf[nt][r] = p;
                rs += p;
            }
            rs += __shfl_xor(rs, 1);
            rs += __shfl_xor(rs, 2);
            rs += __shfl_xor(rs, 4);
            rs += __shfl_xor(rs, 8);
            lsum[r] = lsum[r] * scale + rs;
#pragma unroll
            for (int nt = 0; nt < 4; ++nt) acc[nt][r] *= scale;
        }

        // ---- write P to LDS (bf16, swizzled), re-fragment for PV ----
#pragma unroll
        for (int nt = 0; nt < 4; ++nt) {
            int key = nt * 16 + (lane & 15);
#pragma unroll
            for (int r = 0; r < 4; ++r) {
                int q = (lane >> 4) * 4 + r;
                *(bf16_t*)((char*)&Plds[w][0] + q * 128 +
                           ((key * 2) ^ ((q & 7) << 4))) = (bf16_t)pf[nt][r];
            }
        }
        __syncthreads();

        // ---- O += P V ----
#pragma unroll
        for (int kk = 0; kk < 2; ++kk) {
            int k0 = kk * 32 + (lane >> 4) * 8;
            int q  = lane & 15;
            bf16x8 ap = *(const bf16x8*)((char*)&Plds[w][0] + q * 128 +
                                         ((k0 * 2) ^ ((q & 7) << 4)));
#pragma unroll
            for (int nt = 0; nt < 4; ++nt) {
                int d = nt * 16 + (lane & 15);
                bf16x8 bv = *(const bf16x8*)((char*)Vlds + d * 128 +
                                             ((k0 * 2) ^ ((d & 7) << 4)));
                acc[nt] = __builtin_amdgcn_mfma_f32_16x16x32_bf16(ap, bv, acc[nt], 0, 0, 0);
            }
        }
    }

    // ---- epilogue: normalize and write fp32 ----
    float* ob = out + ((size_t)batch * SS + qtile * 64 + w * 16) * DOUT;
#pragma unroll
    for (int nt = 0; nt < 4; ++nt) {
#pragma unroll
        for (int r = 0; r < 4; ++r) {
            int q = (lane >> 4) * 4 + r;
            int d = nt * 16 + (lane & 15);
            ob[(size_t)q * DOUT + d] = acc[nt][r] / lsum[r];
        }
    }
}

// ---------------------------------------------------------------------------
// Launch. Workspace layout (needs ~6.7 MB):
//   [0, 2MB)   Kp bf16 [8][2048][64]
//   [2, 4MB)   Vp bf16
//   [4, 6MB)   Qp bf16 (pre-scaled by 1/8)
//   [6MB, +384KB) fw bf16 [3][65536] fragment-packed weights
// ---------------------------------------------------------------------------
extern "C" void kernel_launch(void* const* d_in, const int* in_sizes, int n_in,
                              void* d_out, int out_size, void* d_ws, size_t ws_size,
                              hipStream_t stream) {
    const float* Xk = (const float*)d_in[0];
    const float* Xv = (const float*)d_in[1];
    const float* Xq = (const float*)d_in[2];
    const float* Kw = (const float*)d_in[3];
    const float* Vw = (const float*)d_in[4];
    const float* Qw = (const float*)d_in[5];

    bf16_t* Kp = (bf16_t*)d_ws;
    bf16_t* Vp = Kp + (size_t)BB * SS * DOUT;
    bf16_t* Qp = Vp + (size_t)BB * SS * DOUT;
    bf16_t* fw = Qp + (size_t)BB * SS * DOUT;

    prep_weights<<<dim3(48), dim3(256), 0, stream>>>(Kw, Vw, Qw, fw);
    proj_kernel<<<dim3(256, 3), dim3(256), 0, stream>>>(Xk, Xv, Xq, fw, Kp, Vp, Qp);
    attn_kernel<<<dim3(32, 8), dim3(256), 0, stream>>>(Kp, Vp, Qp, (float*)d_out);
}